// Round 1
// baseline (32683.200 us; speedup 1.0000x reference)
//
#include <hip/hip_runtime.h>
#include <hip/hip_bf16.h>
#include <cstdint>
#include <cstddef>

// LSTM_3624952398014 — persistent-kernel LSTM, layer 1 is dead code.
//
// out = relu(h_final(layer0)) @ W_out^T + b_out   -- h1/h0_seq never needed.
//
// Design:
//   256 blocks x 256 thr, cooperative launch. Block (rg,jg) owns batch rows
//   [rg*16,+16) and hidden units [jg*8,+8) => 32 gate rows (i,f,g,o). W slice
//   lives in LDS as bf16 for all 2048 steps; c-state lives in registers.
//   Per step: stage [x_t | h] into LDS (bf16, XOR-swizzled), 16x16x32 bf16
//   MFMA (4 waves = 2 M-tiles x 2 K-halves), LDS K-reduce, gate math, write
//   h chunk to global double buffer, slot-barrier over the 64 blocks of the
//   row group (release store + wave-wide acquire poll; no atomic RMW).

#define B_ 64
#define T_ 2048
#define F_ 128
#define H_ 512

#define RG 4        // row groups
#define JG 64       // j groups
#define ROWS 16     // batch rows per block
#define JS 8        // hidden units per block
#define GATES 32    // 4*JS gate rows per block
#define KTOT 640    // F_ + H_
#define STRIDE_B 1280   // LDS row stride in bytes (640 bf16), 128B-aligned for swizzle
#define NBLK 256
#define NTHR 256

#define W_BASE 0
#define ACT_BASE (GATES * STRIDE_B)              // 40960
#define BIAS_BASE (ACT_BASE + ROWS * STRIDE_B)   // 61440
#define SMEM_SZ (BIAS_BASE + GATES * 4)          // 61568 < 64KB

typedef __bf16 bf16;
typedef __bf16 bf16x4 __attribute__((ext_vector_type(4)));
typedef __bf16 bf16x8 __attribute__((ext_vector_type(8)));
typedef float f32x4 __attribute__((ext_vector_type(4)));

__global__ void __launch_bounds__(NTHR) prep_kernel(unsigned* h0_words, unsigned* slots) {
  int idx = blockIdx.x * blockDim.x + threadIdx.x;
  // zero h_buf[0]: B_*H_ bf16 = 65536 B = 16384 words
  if (idx < (B_ * H_ * 2 / 4)) h0_words[idx] = 0u;
  if (idx < 512) slots[idx] = 0u;
}

__global__ void __launch_bounds__(NTHR) lstm_kernel(
    const float* __restrict__ x,
    const float* __restrict__ Wih,
    const float* __restrict__ Whh,
    const float* __restrict__ bih,
    const float* __restrict__ bhh,
    bf16* __restrict__ h_buf,     // [2][B_][H_] bf16 double buffer
    float* __restrict__ h_f32,    // [B_][H_] final h in fp32
    unsigned* slots)              // [RG][128] step counters (padded groups)
{
  __shared__ __align__(16) char smem[SMEM_SZ];
  float* biasl = (float*)(smem + BIAS_BASE);
  float* Cb = (float*)(smem + ACT_BASE);   // aliases act region between syncs

  const int tid = threadIdx.x;
  const int bid = blockIdx.x;
  const int rg = bid >> 6;        // 0..3
  const int jg = bid & 63;        // 0..63
  const int row0 = rg * ROWS;

  // ---- one-time: W slice -> LDS bf16 (swizzled), bias -> LDS ----
  for (int i = tid; i < GATES * KTOT; i += NTHR) {
    int gl = i / KTOT;
    int k = i - gl * KTOT;
    int q = gl >> 3, jl = gl & 7;
    int Gg = q * H_ + jg * JS + jl;          // global gate row (PyTorch i,f,g,o order)
    float w = (k < F_) ? Wih[(size_t)Gg * F_ + k] : Whh[(size_t)Gg * H_ + (k - F_)];
    int addr = gl * STRIDE_B + ((2 * k) ^ ((gl & 7) << 4));
    *(bf16*)(smem + addr) = (bf16)w;
  }
  if (tid < GATES) {
    int q = tid >> 3, jl = tid & 7;
    int Gg = q * H_ + jg * JS + jl;
    biasl[tid] = bih[Gg] + bhh[Gg];
  }

  // ---- per-thread MFMA fragment constants ----
  const int lane = tid & 63;
  const int wave = tid >> 6;          // 0..3
  const int tile_m = wave & 1;        // which 16 of the 32 gate rows
  const int kh = wave >> 1;           // which K half (320 each)
  const int frag_r = lane & 15;
  const int kboff = (lane >> 4) * 16; // byte offset of lane's 8-elem k group
  const int arow = tile_m * 16 + frag_r;
  const int a_base = arow * STRIDE_B;
  const int a_mask = (arow & 7) << 4;
  const int b_base = ACT_BASE + frag_r * STRIDE_B;
  const int b_mask = (frag_r & 7) << 4;
  const int k0b = kh * 320 * 2;       // byte offset of wave's K-half

  // ---- update-thread constants (tid < 128: one (row, j) cell each) ----
  const int r_u = tid & 15;
  const int jl_u = tid >> 4;          // 0..7 valid when tid<128
  const size_t hidx = (size_t)(row0 + r_u) * H_ + (jg * JS + jl_u);
  float c_state = 0.f;

  unsigned* grp = slots + rg * 128;
  __syncthreads();

  for (int t = 0; t < T_; ++t) {
    // ---- stage activations [x_t | h_prev] -> LDS bf16 (swizzled rows) ----
    const bf16* hcur = h_buf + (size_t)(t & 1) * (B_ * H_);
    for (int i = tid; i < ROWS * F_ / 4; i += NTHR) {          // 512 float4 chunks
      int r = i >> 5, c4 = i & 31;
      const float4 xv = *(const float4*)(x + ((size_t)(row0 + r) * T_ + t) * F_ + c4 * 4);
      bf16x4 bv = { (bf16)xv.x, (bf16)xv.y, (bf16)xv.z, (bf16)xv.w };
      int addr = ACT_BASE + r * STRIDE_B + ((8 * c4) ^ ((r & 7) << 4));
      *(bf16x4*)(smem + addr) = bv;
    }
    for (int i = tid; i < ROWS * H_ / 4; i += NTHR) {          // 2048 bf16x4 chunks
      int r = i >> 7, c4 = i & 127;
      bf16x4 hv = *(const bf16x4*)(hcur + (size_t)(row0 + r) * H_ + c4 * 4);
      int addr = ACT_BASE + r * STRIDE_B + ((256 + 8 * c4) ^ ((r & 7) << 4));
      *(bf16x4*)(smem + addr) = hv;
    }
    __syncthreads();

    // ---- gates GEMM: D[32 gates x 16 rows] += W[g,k] * act[r,k] ----
    f32x4 acc = {0.f, 0.f, 0.f, 0.f};
    #pragma unroll
    for (int kk = 0; kk < 10; ++kk) {
      int kb = k0b + kk * 64 + kboff;
      bf16x8 av = *(const bf16x8*)(smem + a_base + (kb ^ a_mask));
      bf16x8 bv = *(const bf16x8*)(smem + b_base + (kb ^ b_mask));
      acc = __builtin_amdgcn_mfma_f32_16x16x32_bf16(av, bv, acc, 0, 0, 0);
    }
    __syncthreads();   // done reading act; safe to alias as Cb

    // ---- dump partial C tiles (per wave) ----
    {
      float* Cw = Cb + (tile_m * 2 + kh) * 256;
      #pragma unroll
      for (int i = 0; i < 4; ++i) {
        int m = (lane >> 4) * 4 + i;      // D row = 4*(lane>>4)+i
        Cw[m * 16 + (lane & 15)] = acc[i];
      }
    }
    __syncthreads();

    // ---- gate nonlinearity + state update ----
    if (tid < 128) {
      float g4[4];
      #pragma unroll
      for (int q = 0; q < 4; ++q) {
        int gl = q * 8 + jl_u;
        int tile = gl >> 4, m = gl & 15;
        g4[q] = Cb[(tile * 2) * 256 + m * 16 + r_u]
              + Cb[(tile * 2 + 1) * 256 + m * 16 + r_u]
              + biasl[gl];
      }
      float ig = 1.f / (1.f + __expf(-g4[0]));
      float fg = 1.f / (1.f + __expf(-g4[1]));
      float gv = tanhf(g4[2]);
      float og = 1.f / (1.f + __expf(-g4[3]));
      c_state = fg * c_state + ig * gv;
      float hv = og * tanhf(c_state);
      h_buf[(size_t)((t + 1) & 1) * (B_ * H_) + hidx] = (bf16)hv;
      if (t == T_ - 1) h_f32[hidx] = hv;
    }
    __syncthreads();   // all h writes issued before signaling

    // ---- row-group barrier: signal own slot, poll the 64 group slots ----
    if (tid == 0) {
      __threadfence();  // flush h writes to device scope before the flag
      __hip_atomic_store(&grp[jg], (unsigned)(t + 1), __ATOMIC_RELEASE,
                         __HIP_MEMORY_SCOPE_AGENT);
    }
    if (tid < 64) {
      const unsigned tgt = (unsigned)(t + 1);
      while (true) {
        unsigned v = __hip_atomic_load(&grp[lane], __ATOMIC_ACQUIRE,
                                       __HIP_MEMORY_SCOPE_AGENT);
        if (__all((int)(v >= tgt))) break;
        __builtin_amdgcn_s_sleep(2);
      }
    }
    __syncthreads();
  }
}

__global__ void __launch_bounds__(64) out_kernel(
    const float* __restrict__ h_f32,
    const float* __restrict__ Wout,
    const float* __restrict__ bout,
    float* __restrict__ out)
{
  int b = blockIdx.x;
  int lane = threadIdx.x;
  float a0 = 0.f, a1 = 0.f, a2 = 0.f, a3 = 0.f;
  for (int j = lane; j < H_; j += 64) {
    float hv = fmaxf(h_f32[(size_t)b * H_ + j], 0.f);
    a0 += hv * Wout[0 * H_ + j];
    a1 += hv * Wout[1 * H_ + j];
    a2 += hv * Wout[2 * H_ + j];
    a3 += hv * Wout[3 * H_ + j];
  }
  #pragma unroll
  for (int off = 32; off; off >>= 1) {
    a0 += __shfl_down(a0, off);
    a1 += __shfl_down(a1, off);
    a2 += __shfl_down(a2, off);
    a3 += __shfl_down(a3, off);
  }
  if (lane == 0) {
    out[b * 4 + 0] = a0 + bout[0];
    out[b * 4 + 1] = a1 + bout[1];
    out[b * 4 + 2] = a2 + bout[2];
    out[b * 4 + 3] = a3 + bout[3];
  }
}

extern "C" void kernel_launch(void* const* d_in, const int* in_sizes, int n_in,
                              void* d_out, int out_size, void* d_ws, size_t ws_size,
                              hipStream_t stream) {
  const float* x    = (const float*)d_in[0];
  const float* Wih  = (const float*)d_in[1];
  const float* Whh  = (const float*)d_in[2];
  const float* bih  = (const float*)d_in[3];
  const float* bhh  = (const float*)d_in[4];
  // d_in[5..8] = layer-1 weights: dead code in the reference, unused.
  const float* Wout = (const float*)d_in[9];
  const float* bout = (const float*)d_in[10];

  char* ws = (char*)d_ws;
  bf16*     h_buf = (bf16*)ws;                   // 131072 B: [2][64][512] bf16
  float*    hf32  = (float*)(ws + 131072);       // 131072 B: [64][512] f32
  unsigned* slots = (unsigned*)(ws + 262144);    // 2048 B

  hipLaunchKernelGGL(prep_kernel, dim3(64), dim3(NTHR), 0, stream,
                     (unsigned*)h_buf, slots);

  void* args[] = { (void*)&x, (void*)&Wih, (void*)&Whh, (void*)&bih, (void*)&bhh,
                   (void*)&h_buf, (void*)&hf32, (void*)&slots };
  hipLaunchCooperativeKernel((void*)lstm_kernel, dim3(NBLK), dim3(NTHR),
                             args, 0, stream);

  hipLaunchKernelGGL(out_kernel, dim3(B_), dim3(64), 0, stream,
                     hf32, Wout, bout, (float*)d_out);
}

// Round 2
// 6190.819 us; speedup vs baseline: 5.2793x; 5.2793x over previous
//
#include <hip/hip_runtime.h>
#include <hip/hip_bf16.h>
#include <cstdint>
#include <cstddef>

// LSTM_3624952398014 — R2: barrier-free tagged-payload LSTM.
// Layer 1 of the reference is dead code; out = relu(h_final(L0)) @ W_out^T + b.
//
// 128 blocks (4 row-groups x 32 j-groups) x 256 thr, cooperative.
// Block owns 16 batch rows x 16 hidden units (64 gate rows).
// W_ih|W_hh slice lives in REGISTERS (20 bf16x8 A-frags/lane) for all steps.
// Cross-block h exchange: 8-byte words {tag(step)<<32 | 2 x bf16}, written
// with global_store_dwordx2 sc0 sc1 (write-through to coherent LLC) and read
// with global_load_dwordx2 sc0 sc1 (bypass per-XCD L2). Tag+data share one
// atomic 64-bit access => no fences, no acquire/release, no barrier, and no
// L2 writeback/invalidate storms (R1's 16us/step cost).

#define B_ 64
#define T_ 2048
#define F_ 128
#define H_ 512

#define RG 4
#define JG 32
#define ROWS 16
#define JUNITS 16
#define KCH 20            // K=640 in chunks of 32: 4 x-chunks + 16 h-chunks
#define NBLK 128
#define NTHR 256

#define ACT_STRIDE 1280                     // 640 bf16 per act row
#define C_BASE (ROWS * ACT_STRIDE)          // 20480
#define C_TILE 272                          // 16*17 f32 (padded)
#define BIAS_BASE (C_BASE + 4 * C_TILE * 4) // 24832
#define SMEM_SZ (BIAS_BASE + 64 * 4)        // 25088 B

#define HWORDS_ROW 256                      // u64 words per row (512 units / 2)
#define HSLOT (B_ * HWORDS_ROW)             // 16384 u64 per slot

typedef __bf16 bf16;
typedef __bf16 bf16x4 __attribute__((ext_vector_type(4)));
typedef __bf16 bf16x8 __attribute__((ext_vector_type(8)));
typedef float f32x4 __attribute__((ext_vector_type(4)));

static __device__ __forceinline__ float sigm(float v) {
  return 1.f / (1.f + __expf(-v));
}
static __device__ __forceinline__ float tanh_f(float v) {
  float a = fminf(fabsf(v), 20.f);
  float e = __expf(-2.f * a);
  float t = 1.f - 2.f * e / (1.f + e);
  return copysignf(t, v);
}
static __device__ __forceinline__ unsigned bf16bits(float f) {
  bf16 b = (bf16)f;
  unsigned short us;
  __builtin_memcpy(&us, &b, 2);
  return (unsigned)us;
}

__global__ void __launch_bounds__(NTHR) prep_kernel(unsigned long long* hbuf) {
  int idx = blockIdx.x * blockDim.x + threadIdx.x;   // 128*256 = 32768 = 2*HSLOT
  hbuf[idx] = 0ULL;                                  // tag 0 == h_0 == zeros
}

__global__ void __launch_bounds__(NTHR) lstm_kernel(
    const float* __restrict__ x,
    const float* __restrict__ Wih,
    const float* __restrict__ Whh,
    const float* __restrict__ bih,
    const float* __restrict__ bhh,
    unsigned long long* __restrict__ hbuf,   // [2][B_][HWORDS_ROW] tagged u64
    float* __restrict__ hf32)                // [B_][H_] final h fp32
{
  __shared__ __align__(16) char smem[SMEM_SZ];
  float* Cb = (float*)(smem + C_BASE);
  float* biasl = (float*)(smem + BIAS_BASE);

  const int tid = threadIdx.x;
  const int bid = blockIdx.x;
  const int rg = bid >> 5;          // 0..3
  const int jg = bid & 31;          // 0..31
  const int row0 = rg * ROWS;
  const int j0 = jg * JUNITS;

  const int lane = tid & 63;
  const int wave = tid >> 6;        // = gate type q (i,f,g,o)
  const int fr = lane & 15;
  const int kg = lane >> 4;         // 0..3

  // ---- one-time: W slice -> register A-fragments (stays for all 2048 steps)
  bf16x8 wfrag[KCH];
  {
    const int G = wave * H_ + j0 + fr;            // global gate row
    const float* sih = Wih + (size_t)G * F_;
    const float* shh = Whh + (size_t)G * H_;
    #pragma unroll
    for (int kk = 0; kk < KCH; ++kk) {
      const float* s = (kk < 4) ? (sih + kk * 32 + kg * 8)
                                : (shh + (kk - 4) * 32 + kg * 8);
      float4 f0 = *(const float4*)s;
      float4 f1 = *(const float4*)(s + 4);
      bf16x8 w = { (bf16)f0.x, (bf16)f0.y, (bf16)f0.z, (bf16)f0.w,
                   (bf16)f1.x, (bf16)f1.y, (bf16)f1.z, (bf16)f1.w };
      wfrag[kk] = w;
    }
  }
  if (tid < 64) {
    int q = tid >> 4, jj = tid & 15;
    int G = q * H_ + j0 + jj;
    biasl[tid] = bih[G] + bhh[G];
  }

  // poll/staging constants: thread handles act row `prow`, words i*16+pw
  const int prow = tid >> 4;        // 0..15
  const int pw = tid & 15;
  // x staging: items tid (rows 0..7) and tid+256 (rows 8..15)
  const int r0x = tid >> 5;         // 0..7
  const int c40 = tid & 31;
  // gate-math constants (tid < 128): 2 adjacent cells each
  const int grow = tid >> 3;        // 0..15
  const int jl2 = tid & 7;          // 0..7
  float c0 = 0.f, c1 = 0.f;

  __syncthreads();

  for (int t = 0; t < T_; ++t) {
    // ---- stage x_t (load f32, round to bf16, swizzled LDS write) ----
    {
      float4 xv0 = *(const float4*)(x + ((size_t)(row0 + r0x) * T_ + t) * F_ + c40 * 4);
      float4 xv1 = *(const float4*)(x + ((size_t)(row0 + r0x + 8) * T_ + t) * F_ + c40 * 4);
      bf16x4 b0 = { (bf16)xv0.x, (bf16)xv0.y, (bf16)xv0.z, (bf16)xv0.w };
      bf16x4 b1 = { (bf16)xv1.x, (bf16)xv1.y, (bf16)xv1.z, (bf16)xv1.w };
      *(bf16x4*)(smem + r0x * ACT_STRIDE + ((8 * c40) ^ ((r0x & 7) << 4))) = b0;
      *(bf16x4*)(smem + (r0x + 8) * ACT_STRIDE + ((8 * c40) ^ (((r0x + 8) & 7) << 4))) = b1;
    }

    // ---- poll h_t: 16 tagged u64 per thread, single LLC round trip ----
    unsigned long long v[16];
    const unsigned long long* hb =
        hbuf + (size_t)(t & 1) * HSLOT + (size_t)(row0 + prow) * HWORDS_ROW + pw;
    const unsigned tgt = (unsigned)t;
    while (true) {
      #pragma unroll
      for (int i = 0; i < 16; ++i) {
        const unsigned long long* p = hb + i * 16;
        asm volatile("global_load_dwordx2 %0, %1, off sc0 sc1"
                     : "=v"(v[i]) : "v"(p));
      }
      asm volatile("s_waitcnt vmcnt(0)" ::: "memory");
      bool ok = true;
      #pragma unroll
      for (int i = 0; i < 16; ++i) ok &= ((unsigned)(v[i] >> 32) == tgt);
      if (ok) break;
      __builtin_amdgcn_s_sleep(1);
    }
    // unpack h payloads -> act LDS (h occupies bytes [256,1280) of each row)
    #pragma unroll
    for (int i = 0; i < 16; ++i) {
      unsigned pay = (unsigned)v[i];
      int w = i * 16 + pw;
      *(unsigned*)(smem + prow * ACT_STRIDE + ((256 + 4 * w) ^ ((prow & 7) << 4))) = pay;
    }
    __syncthreads();

    // ---- gates GEMM: D[16 gates x 16 rows] per wave, K=640 ----
    f32x4 a0 = {0.f, 0.f, 0.f, 0.f}, a1 = {0.f, 0.f, 0.f, 0.f};
    {
      const char* bbase = smem + fr * ACT_STRIDE;
      const int bmask = (fr & 7) << 4;
      #pragma unroll
      for (int kk = 0; kk < KCH; kk += 2) {
        bf16x8 b0 = *(const bf16x8*)(bbase + ((kk * 64 + kg * 16) ^ bmask));
        a0 = __builtin_amdgcn_mfma_f32_16x16x32_bf16(wfrag[kk], b0, a0, 0, 0, 0);
        bf16x8 b1 = *(const bf16x8*)(bbase + (((kk + 1) * 64 + kg * 16) ^ bmask));
        a1 = __builtin_amdgcn_mfma_f32_16x16x32_bf16(wfrag[kk + 1], b1, a1, 0, 0, 0);
      }
    }
    f32x4 d = a0 + a1;
    {
      float* Cw = Cb + wave * C_TILE;
      #pragma unroll
      for (int i = 0; i < 4; ++i)
        Cw[(kg * 4 + i) * 17 + fr] = d[i];    // C[q][gate jl][row r], pad 17
    }
    __syncthreads();

    // ---- gate math: tid<128, two adjacent cells (grow, 2*jl2 / 2*jl2+1) ----
    if (tid < 128) {
      float g0[4], g1[4];
      #pragma unroll
      for (int q = 0; q < 4; ++q) {
        g0[q] = Cb[q * C_TILE + (2 * jl2 + 0) * 17 + grow] + biasl[q * 16 + 2 * jl2 + 0];
        g1[q] = Cb[q * C_TILE + (2 * jl2 + 1) * 17 + grow] + biasl[q * 16 + 2 * jl2 + 1];
      }
      float i0 = sigm(g0[0]), f0g = sigm(g0[1]), gg0 = tanh_f(g0[2]), o0 = sigm(g0[3]);
      float i1 = sigm(g1[0]), f1g = sigm(g1[1]), gg1 = tanh_f(g1[2]), o1 = sigm(g1[3]);
      c0 = f0g * c0 + i0 * gg0;
      c1 = f1g * c1 + i1 * gg1;
      float h0v = o0 * tanh_f(c0);
      float h1v = o1 * tanh_f(c1);

      unsigned pay = bf16bits(h0v) | (bf16bits(h1v) << 16);
      unsigned long long val = (unsigned long long)pay
                             | ((unsigned long long)(unsigned)(t + 1) << 32);
      unsigned long long* dst = hbuf + (size_t)((t + 1) & 1) * HSLOT
                              + (size_t)(row0 + grow) * HWORDS_ROW + (j0 >> 1) + jl2;
      asm volatile("global_store_dwordx2 %0, %1, off sc0 sc1"
                   :: "v"(dst), "v"(val) : "memory");

      if (t == T_ - 1) {
        float2 hf = { h0v, h1v };
        *(float2*)(hf32 + (size_t)(row0 + grow) * H_ + j0 + 2 * jl2) = hf;
      }
    }
  }
}

__global__ void __launch_bounds__(64) out_kernel(
    const float* __restrict__ h_f32,
    const float* __restrict__ Wout,
    const float* __restrict__ bout,
    float* __restrict__ out)
{
  int b = blockIdx.x;
  int lane = threadIdx.x;
  float a0 = 0.f, a1 = 0.f, a2 = 0.f, a3 = 0.f;
  for (int j = lane; j < H_; j += 64) {
    float hv = fmaxf(h_f32[(size_t)b * H_ + j], 0.f);
    a0 += hv * Wout[0 * H_ + j];
    a1 += hv * Wout[1 * H_ + j];
    a2 += hv * Wout[2 * H_ + j];
    a3 += hv * Wout[3 * H_ + j];
  }
  #pragma unroll
  for (int off = 32; off; off >>= 1) {
    a0 += __shfl_down(a0, off);
    a1 += __shfl_down(a1, off);
    a2 += __shfl_down(a2, off);
    a3 += __shfl_down(a3, off);
  }
  if (lane == 0) {
    out[b * 4 + 0] = a0 + bout[0];
    out[b * 4 + 1] = a1 + bout[1];
    out[b * 4 + 2] = a2 + bout[2];
    out[b * 4 + 3] = a3 + bout[3];
  }
}

extern "C" void kernel_launch(void* const* d_in, const int* in_sizes, int n_in,
                              void* d_out, int out_size, void* d_ws, size_t ws_size,
                              hipStream_t stream) {
  const float* x    = (const float*)d_in[0];
  const float* Wih  = (const float*)d_in[1];
  const float* Whh  = (const float*)d_in[2];
  const float* bih  = (const float*)d_in[3];
  const float* bhh  = (const float*)d_in[4];
  // d_in[5..8] = layer-1 weights: dead code in the reference, unused.
  const float* Wout = (const float*)d_in[9];
  const float* bout = (const float*)d_in[10];

  char* ws = (char*)d_ws;
  unsigned long long* hbuf = (unsigned long long*)ws;       // 262144 B
  float* hf32 = (float*)(ws + 262144);                      // 131072 B

  hipLaunchKernelGGL(prep_kernel, dim3(NBLK), dim3(NTHR), 0, stream, hbuf);

  void* args[] = { (void*)&x, (void*)&Wih, (void*)&Whh, (void*)&bih, (void*)&bhh,
                   (void*)&hbuf, (void*)&hf32 };
  hipLaunchCooperativeKernel((void*)lstm_kernel, dim3(NBLK), dim3(NTHR),
                             args, 0, stream);

  hipLaunchKernelGGL(out_kernel, dim3(B_), dim3(64), 0, stream,
                     hf32, Wout, bout, (float*)d_out);
}

// Round 3
// 5386.617 us; speedup vs baseline: 6.0675x; 1.1493x over previous
//
#include <hip/hip_runtime.h>
#include <hip/hip_bf16.h>
#include <cstdint>
#include <cstddef>

// LSTM_3624952398014 — R3: tagged-LLC exchange + single-sync step + in-lane
// gate math via 4x4 lane transpose of the MFMA D-fragment.
//
// Layer 1 of the reference is dead code; out = relu(h_final(L0)) @ W_out^T + b.
//
// 128 blocks (4 row-groups x 32 j-groups) x 256 thr, cooperative.
// Block owns 16 batch rows x 16 hidden units. Wave w owns j-units
// [j0+4w, j0+4w+4) x 4 gate types (M-tile rows m = q*4+jl). After the MFMA,
// a 4x4 transpose across lane groups (shfl_xor 32 then 16) gives each lane
// all 4 gate values of one (b,j) cell -> gate math in-lane, c in 1 VGPR.
// Cross-block h exchange: u32 words {tag16 | bf16 h} stored/loaded with
// sc0 sc1 (device-coherent LLC, bypasses the non-coherent per-XCD L2).

#define B_ 64
#define T_ 2048
#define F_ 128
#define H_ 512

#define NBLK 128
#define NTHR 256

#define ACT_STRIDE 1280                 // 640 bf16 per act row
#define BUF_SZ (16 * ACT_STRIDE)        // 20480 B per buffer
#define SMEM_SZ (2 * BUF_SZ)            // 40960 B
#define HSLOT (B_ * H_)                 // 32768 u32 words per slot

typedef __bf16 bf16;
typedef __bf16 bf16x4 __attribute__((ext_vector_type(4)));
typedef __bf16 bf16x8 __attribute__((ext_vector_type(8)));
typedef float f32x4 __attribute__((ext_vector_type(4)));
typedef unsigned int u32;
typedef u32 u32x2 __attribute__((ext_vector_type(2)));
typedef u32 u32x4 __attribute__((ext_vector_type(4)));

static __device__ __forceinline__ float sigm(float v) {
  return 1.f / (1.f + __expf(-v));
}
static __device__ __forceinline__ float tanh_f(float v) {
  float a = fminf(fabsf(v), 20.f);
  float e = __expf(-2.f * a);
  float t = 1.f - 2.f * e / (1.f + e);
  return copysignf(t, v);
}
static __device__ __forceinline__ u32 bf16bits(float f) {
  bf16 b = (bf16)f;
  unsigned short us;
  __builtin_memcpy(&us, &b, 2);
  return (u32)us;
}

__global__ void __launch_bounds__(NTHR) prep_kernel(u32* hbuf) {
  int idx = blockIdx.x * blockDim.x + threadIdx.x;   // 128*256 = 32768 = HSLOT
  if (idx < HSLOT) hbuf[idx] = 0u;                   // slot 0: tag 0, h = 0
}

__global__ void __launch_bounds__(NTHR, 1) lstm_kernel(
    const float* __restrict__ x,
    const float* __restrict__ Wih,
    const float* __restrict__ Whh,
    const float* __restrict__ bih,
    const float* __restrict__ bhh,
    u32* __restrict__ hbuf,        // [2][B_][H_] tagged u32
    float* __restrict__ hf32)      // [B_][H_] final h fp32
{
  __shared__ __align__(16) char smem[SMEM_SZ];

  const int tid = threadIdx.x;
  const int bid = blockIdx.x;
  const int rg = bid >> 5;          // 0..3
  const int jg = bid & 31;          // 0..31
  const int row0 = rg * 16;
  const int j0 = jg * 16;

  const int lane = tid & 63;
  const int wave = tid >> 6;        // 0..3
  const int fr = lane & 15;
  const int kg = lane >> 4;         // 0..3

  // ---- one-time: W slice -> register A-fragments ----
  // A-tile row m = fr maps to gate type q = fr>>2, j-local jl = fr&3.
  bf16x8 wfrag[20];
  {
    const int G = (fr >> 2) * H_ + j0 + wave * 4 + (fr & 3);
    const float* sih = Wih + (size_t)G * F_;
    const float* shh = Whh + (size_t)G * H_;
    #pragma unroll
    for (int kk = 0; kk < 20; ++kk) {
      const float* s = (kk < 4) ? (sih + kk * 32 + kg * 8)
                                : (shh + (kk - 4) * 32 + kg * 8);
      float4 f0 = *(const float4*)s;
      float4 f1 = *(const float4*)(s + 4);
      bf16x8 w = { (bf16)f0.x, (bf16)f0.y, (bf16)f0.z, (bf16)f0.w,
                   (bf16)f1.x, (bf16)f1.y, (bf16)f1.z, (bf16)f1.w };
      wfrag[kk] = w;
    }
  }

  // ---- per-lane cell (post-transpose): b = row0+fr, j = j0 + wave*4 + kg ----
  const int jcol = j0 + wave * 4 + kg;
  const float bi_ = bih[0 * H_ + jcol] + bhh[0 * H_ + jcol];
  const float bf_ = bih[1 * H_ + jcol] + bhh[1 * H_ + jcol];
  const float bg_ = bih[2 * H_ + jcol] + bhh[2 * H_ + jcol];
  const float bo_ = bih[3 * H_ + jcol] + bhh[3 * H_ + jcol];

  // poll/unpack ids: row prow, 8 chunks of 4 j at c = i*16 + pw
  const int prow = tid >> 4;        // 0..15
  const int pw = tid & 15;
  // x staging ids
  const int r0x = tid >> 5;         // 0..7
  const int c40 = tid & 31;
  const float* xp0 = x + (size_t)(row0 + r0x) * T_ * F_ + c40 * 4;
  const float* xp1 = x + (size_t)(row0 + r0x + 8) * T_ * F_ + c40 * 4;
  const int xw0 = r0x * ACT_STRIDE + ((8 * c40) ^ ((r0x & 7) << 4));
  const int xw1 = (r0x + 8) * ACT_STRIDE + ((8 * c40) ^ (((r0x + 8) & 7) << 4));

  float c_state = 0.f;

  for (int t = 0; t < T_; ++t) {
    char* buf = smem + (t & 1) * BUF_SZ;

    // ---- stage x_t (f32 -> bf16, conflict-free swizzled writes) ----
    {
      float4 xv0 = *(const float4*)(xp0 + (size_t)t * F_);
      float4 xv1 = *(const float4*)(xp1 + (size_t)t * F_);
      bf16x4 b0 = { (bf16)xv0.x, (bf16)xv0.y, (bf16)xv0.z, (bf16)xv0.w };
      bf16x4 b1 = { (bf16)xv1.x, (bf16)xv1.y, (bf16)xv1.z, (bf16)xv1.w };
      *(bf16x4*)(buf + xw0) = b0;
      *(bf16x4*)(buf + xw1) = b1;
    }

    // ---- poll h_t: 8 dwordx4 (32 tagged u32) per thread ----
    u32x4 v0, v1, v2, v3, v4, v5, v6, v7;
    {
      const u32* hb = hbuf + (size_t)(t & 1) * HSLOT + (size_t)(row0 + prow) * H_ + 4 * pw;
      const u32 tgt = (u32)t << 16;
      while (true) {
        asm volatile("global_load_dwordx4 %0, %1, off sc0 sc1" : "=v"(v0) : "v"(hb + 0 * 64));
        asm volatile("global_load_dwordx4 %0, %1, off sc0 sc1" : "=v"(v1) : "v"(hb + 1 * 64));
        asm volatile("global_load_dwordx4 %0, %1, off sc0 sc1" : "=v"(v2) : "v"(hb + 2 * 64));
        asm volatile("global_load_dwordx4 %0, %1, off sc0 sc1" : "=v"(v3) : "v"(hb + 3 * 64));
        asm volatile("global_load_dwordx4 %0, %1, off sc0 sc1" : "=v"(v4) : "v"(hb + 4 * 64));
        asm volatile("global_load_dwordx4 %0, %1, off sc0 sc1" : "=v"(v5) : "v"(hb + 5 * 64));
        asm volatile("global_load_dwordx4 %0, %1, off sc0 sc1" : "=v"(v6) : "v"(hb + 6 * 64));
        asm volatile("global_load_dwordx4 %0, %1, off sc0 sc1" : "=v"(v7) : "v"(hb + 7 * 64));
        asm volatile("s_waitcnt vmcnt(0)" ::: "memory");
        __builtin_amdgcn_sched_barrier(0);   // rule #18: no hoist of tag checks
        bool ok = true;
        #pragma unroll
        for (int j = 0; j < 4; ++j) {
          ok &= ((v0[j] & 0xFFFF0000u) == tgt);
          ok &= ((v1[j] & 0xFFFF0000u) == tgt);
          ok &= ((v2[j] & 0xFFFF0000u) == tgt);
          ok &= ((v3[j] & 0xFFFF0000u) == tgt);
          ok &= ((v4[j] & 0xFFFF0000u) == tgt);
          ok &= ((v5[j] & 0xFFFF0000u) == tgt);
          ok &= ((v6[j] & 0xFFFF0000u) == tgt);
          ok &= ((v7[j] & 0xFFFF0000u) == tgt);
        }
        if (ok) break;
        __builtin_amdgcn_s_sleep(1);
      }
    }
    // ---- unpack payloads -> act LDS (16 lanes x 8B contiguous = no conflict)
    {
      char* dst = buf + prow * ACT_STRIDE;
      const int swz = (prow & 7) << 4;
      #define UNPACK(i, V)                                                  \
        {                                                                   \
          u32 w0 = (V[0] & 0xffffu) | (V[1] << 16);                         \
          u32 w1 = (V[2] & 0xffffu) | (V[3] << 16);                         \
          u32x2 wp = { w0, w1 };                                            \
          *(u32x2*)(dst + ((256 + 128 * (i) + 8 * pw) ^ swz)) = wp;         \
        }
      UNPACK(0, v0) UNPACK(1, v1) UNPACK(2, v2) UNPACK(3, v3)
      UNPACK(4, v4) UNPACK(5, v5) UNPACK(6, v6) UNPACK(7, v7)
      #undef UNPACK
    }
    __syncthreads();

    // ---- gates GEMM: per-wave 16x16, K=640 ----
    f32x4 a0 = {0.f, 0.f, 0.f, 0.f}, a1 = {0.f, 0.f, 0.f, 0.f};
    {
      const char* bbase = buf + fr * ACT_STRIDE;
      const int bmask = (fr & 7) << 4;
      #pragma unroll
      for (int kk = 0; kk < 20; kk += 2) {
        bf16x8 b0 = *(const bf16x8*)(bbase + ((kk * 64 + kg * 16) ^ bmask));
        a0 = __builtin_amdgcn_mfma_f32_16x16x32_bf16(wfrag[kk], b0, a0, 0, 0, 0);
        bf16x8 b1 = *(const bf16x8*)(bbase + (((kk + 1) * 64 + kg * 16) ^ bmask));
        a1 = __builtin_amdgcn_mfma_f32_16x16x32_bf16(wfrag[kk + 1], b1, a1, 0, 0, 0);
      }
    }
    f32x4 dsum = a0 + a1;
    // lane (fr,kg) holds D rows m=kg*4+i => type q=kg, jl=i, for batch row fr.

    // ---- 4x4 transpose across lane groups (kg) -> lane gets 4 types of j=jl=kg
    float d0 = dsum[0], d1 = dsum[1], d2 = dsum[2], d3 = dsum[3];
    float t0 = __shfl_xor((kg & 2) ? d0 : d2, 32, 64);
    float t1 = __shfl_xor((kg & 2) ? d1 : d3, 32, 64);
    float w0 = (kg & 2) ? t0 : d0;
    float w1 = (kg & 2) ? t1 : d1;
    float w2 = (kg & 2) ? d2 : t0;
    float w3 = (kg & 2) ? d3 : t1;
    float t2 = __shfl_xor((kg & 1) ? w0 : w1, 16, 64);
    float t3 = __shfl_xor((kg & 1) ? w2 : w3, 16, 64);
    float gi = (kg & 1) ? t2 : w0;
    float gf = (kg & 1) ? w1 : t2;
    float gg = (kg & 1) ? t3 : w2;
    float go = (kg & 1) ? w3 : t3;

    // ---- gate math + state update (1 cell per lane) ----
    float iv = sigm(gi + bi_);
    float fv = sigm(gf + bf_);
    float gv = tanh_f(gg + bg_);
    float ov = sigm(go + bo_);
    c_state = fv * c_state + iv * gv;
    float hv = ov * tanh_f(c_state);

    // ---- tagged store ----
    u32 val = ((u32)(t + 1) << 16) | bf16bits(hv);
    u32* dstp = hbuf + (size_t)((t + 1) & 1) * HSLOT + (size_t)(row0 + fr) * H_ + jcol;
    asm volatile("global_store_dword %0, %1, off sc0 sc1" :: "v"(dstp), "v"(val) : "memory");

    if (t == T_ - 1) hf32[(size_t)(row0 + fr) * H_ + jcol] = hv;
  }
}

__global__ void __launch_bounds__(64) out_kernel(
    const float* __restrict__ h_f32,
    const float* __restrict__ Wout,
    const float* __restrict__ bout,
    float* __restrict__ out)
{
  int b = blockIdx.x;
  int lane = threadIdx.x;
  float a0 = 0.f, a1 = 0.f, a2 = 0.f, a3 = 0.f;
  for (int j = lane; j < H_; j += 64) {
    float hv = fmaxf(h_f32[(size_t)b * H_ + j], 0.f);
    a0 += hv * Wout[0 * H_ + j];
    a1 += hv * Wout[1 * H_ + j];
    a2 += hv * Wout[2 * H_ + j];
    a3 += hv * Wout[3 * H_ + j];
  }
  #pragma unroll
  for (int off = 32; off; off >>= 1) {
    a0 += __shfl_down(a0, off);
    a1 += __shfl_down(a1, off);
    a2 += __shfl_down(a2, off);
    a3 += __shfl_down(a3, off);
  }
  if (lane == 0) {
    out[b * 4 + 0] = a0 + bout[0];
    out[b * 4 + 1] = a1 + bout[1];
    out[b * 4 + 2] = a2 + bout[2];
    out[b * 4 + 3] = a3 + bout[3];
  }
}

extern "C" void kernel_launch(void* const* d_in, const int* in_sizes, int n_in,
                              void* d_out, int out_size, void* d_ws, size_t ws_size,
                              hipStream_t stream) {
  const float* x    = (const float*)d_in[0];
  const float* Wih  = (const float*)d_in[1];
  const float* Whh  = (const float*)d_in[2];
  const float* bih  = (const float*)d_in[3];
  const float* bhh  = (const float*)d_in[4];
  // d_in[5..8] = layer-1 weights: dead code in the reference, unused.
  const float* Wout = (const float*)d_in[9];
  const float* bout = (const float*)d_in[10];

  char* ws = (char*)d_ws;
  u32*   hbuf = (u32*)ws;                    // 2*32768*4 = 262144 B
  float* hf32 = (float*)(ws + 262144);       // 131072 B

  hipLaunchKernelGGL(prep_kernel, dim3(NBLK), dim3(NTHR), 0, stream, hbuf);

  void* args[] = { (void*)&x, (void*)&Wih, (void*)&Whh, (void*)&bih, (void*)&bhh,
                   (void*)&hbuf, (void*)&hf32 };
  hipLaunchCooperativeKernel((void*)lstm_kernel, dim3(NBLK), dim3(NTHR),
                             args, 0, stream);

  hipLaunchKernelGGL(out_kernel, dim3(B_), dim3(64), 0, stream,
                     hf32, Wout, bout, (float*)d_out);
}

// Round 4
// 4203.838 us; speedup vs baseline: 7.7746x; 1.2814x over previous
//
#include <hip/hip_runtime.h>
#include <hip/hip_bf16.h>
#include <cstdint>
#include <cstddef>

// LSTM_3624952398014 — R4: tagged-LLC exchange, x pre-converted to bf16 and
// re-laid [T][rg][16][128] (L2-hot 16KB/step), poll loads issued under the
// x-chunk MFMAs, min-tree tag check, hard spin, single LDS buffer.
//
// Layer 1 of the reference is dead code; out = relu(h_final(L0)) @ W_out^T + b.

#define B_ 64
#define T_ 2048
#define F_ 128
#define H_ 512

#define NBLK 128
#define NTHR 256

#define ACT_STRIDE 1280                 // 640 bf16 per act row
#define SMEM_SZ (16 * ACT_STRIDE)       // 20480 B
#define HSLOT (B_ * H_)                 // 32768 u32 words per slot

typedef __bf16 bf16;
typedef __bf16 bf16x4 __attribute__((ext_vector_type(4)));
typedef __bf16 bf16x8 __attribute__((ext_vector_type(8)));
typedef float f32x4 __attribute__((ext_vector_type(4)));
typedef unsigned int u32;
typedef u32 u32x2 __attribute__((ext_vector_type(2)));
typedef u32 u32x4 __attribute__((ext_vector_type(4)));

static __device__ __forceinline__ float sigm(float v) {
  return 1.f / (1.f + __expf(-v));
}
static __device__ __forceinline__ float tanh_f(float v) {
  float a = fminf(fabsf(v), 20.f);
  float e = __expf(-2.f * a);
  float t = 1.f - 2.f * e / (1.f + e);
  return copysignf(t, v);
}
static __device__ __forceinline__ u32 bf16bits(float f) {
  bf16 b = (bf16)f;
  unsigned short us;
  __builtin_memcpy(&us, &b, 2);
  return (u32)us;
}

__global__ void __launch_bounds__(NTHR) prep_kernel(u32* hbuf) {
  int idx = blockIdx.x * blockDim.x + threadIdx.x;   // 256*256 = 65536 = 2*HSLOT
  hbuf[idx] = 0u;   // both slots: tag 0, h = 0 (monotone-min soundness)
}

// x [B][T][F] f32  ->  xbf [T][4 rg][16 row][128] bf16
__global__ void __launch_bounds__(NTHR) xconv_kernel(
    const float* __restrict__ x, bf16* __restrict__ xbf) {
  const int b = blockIdx.x;          // 0..63
  const int t0 = blockIdx.y * 256;   // grid.y = 8
  const int f2 = threadIdx.x & 63;   // 2 floats per thread
  const int tq = threadIdx.x >> 6;   // 0..3
  const int rg = b >> 4, row = b & 15;
  for (int i = 0; i < 64; ++i) {
    int t = t0 + i * 4 + tq;
    float2 xv = *(const float2*)(x + ((size_t)b * T_ + t) * F_ + 2 * f2);
    u32 w = bf16bits(xv.x) | (bf16bits(xv.y) << 16);
    *(u32*)((char*)xbf + ((((size_t)t * 4 + rg) * 16 + row) * 128 + 2 * f2) * 2) = w;
  }
}

__global__ void __launch_bounds__(NTHR, 1) lstm_kernel(
    const float* __restrict__ x,
    const float* __restrict__ Wih,
    const float* __restrict__ Whh,
    const float* __restrict__ bih,
    const float* __restrict__ bhh,
    u32* __restrict__ hbuf,        // [2][B_][H_] tagged u32
    float* __restrict__ hf32,      // [B_][H_] final h fp32
    const bf16* __restrict__ xbf)  // [T][4][16][128] bf16 or nullptr
{
  __shared__ __align__(16) char smem[SMEM_SZ];

  const int tid = threadIdx.x;
  const int bid = blockIdx.x;
  const int rg = bid >> 5;          // 0..3
  const int jg = bid & 31;          // 0..31
  const int row0 = rg * 16;
  const int j0 = jg * 16;

  const int lane = tid & 63;
  const int wave = tid >> 6;        // 0..3
  const int fr = lane & 15;
  const int kg = lane >> 4;         // 0..3

  // ---- one-time: W slice -> register A-fragments ----
  bf16x8 wfrag[20];
  {
    const int G = (fr >> 2) * H_ + j0 + wave * 4 + (fr & 3);
    const float* sih = Wih + (size_t)G * F_;
    const float* shh = Whh + (size_t)G * H_;
    #pragma unroll
    for (int kk = 0; kk < 20; ++kk) {
      const float* s = (kk < 4) ? (sih + kk * 32 + kg * 8)
                                : (shh + (kk - 4) * 32 + kg * 8);
      float4 f0 = *(const float4*)s;
      float4 f1 = *(const float4*)(s + 4);
      bf16x8 w = { (bf16)f0.x, (bf16)f0.y, (bf16)f0.z, (bf16)f0.w,
                   (bf16)f1.x, (bf16)f1.y, (bf16)f1.z, (bf16)f1.w };
      wfrag[kk] = w;
    }
  }

  // per-lane cell (post-transpose): b = row0+fr, j = j0 + wave*4 + kg
  const int jcol = j0 + wave * 4 + kg;
  const float bi_ = bih[0 * H_ + jcol] + bhh[0 * H_ + jcol];
  const float bf_ = bih[1 * H_ + jcol] + bhh[1 * H_ + jcol];
  const float bg_ = bih[2 * H_ + jcol] + bhh[2 * H_ + jcol];
  const float bo_ = bih[3 * H_ + jcol] + bhh[3 * H_ + jcol];

  // poll/unpack ids
  const int prow = tid >> 4;        // 0..15
  const int pw = tid & 15;
  // f32-fallback x staging ids
  const int r0x = tid >> 5;
  const int c40 = tid & 31;
  const float* xp0 = x + (size_t)(row0 + r0x) * T_ * F_ + c40 * 4;
  const float* xp1 = x + (size_t)(row0 + r0x + 8) * T_ * F_ + c40 * 4;
  const int xw0 = r0x * ACT_STRIDE + ((8 * c40) ^ ((r0x & 7) << 4));
  const int xw1 = (r0x + 8) * ACT_STRIDE + ((8 * c40) ^ (((r0x + 8) & 7) << 4));
  // bf16 x staging ids
  const int xrow = tid >> 4;
  const int xseg = tid & 15;
  const int xw = xrow * ACT_STRIDE + ((xseg * 16) ^ ((xrow & 7) << 4));

  char* buf = smem;
  float c_state = 0.f;

  for (int t = 0; t < T_; ++t) {
    // ---- stage x_t into LDS x-region [0,256)B per row ----
    if (xbf) {
      u32x4 xv = *(const u32x4*)((const char*)xbf
                  + ((size_t)t * 4 + rg) * 4096 + tid * 16);
      *(u32x4*)(buf + xw) = xv;
    } else {
      float4 xv0 = *(const float4*)(xp0 + (size_t)t * F_);
      float4 xv1 = *(const float4*)(xp1 + (size_t)t * F_);
      bf16x4 b0 = { (bf16)xv0.x, (bf16)xv0.y, (bf16)xv0.z, (bf16)xv0.w };
      bf16x4 b1 = { (bf16)xv1.x, (bf16)xv1.y, (bf16)xv1.z, (bf16)xv1.w };
      *(bf16x4*)(buf + xw0) = b0;
      *(bf16x4*)(buf + xw1) = b1;
    }
    __syncthreads();   // sync1: x region ready; prior step fully consumed

    // ---- issue poll loads, then hide x-chunk MFMAs under the LLC latency ----
    u32x4 v0, v1, v2, v3, v4, v5, v6, v7;
    const u32* hb = hbuf + (size_t)(t & 1) * HSLOT + (size_t)(row0 + prow) * H_ + 4 * pw;
    #define ISSUE_POLLS()                                                               \
      asm volatile("global_load_dwordx4 %0, %1, off sc0 sc1" : "=v"(v0) : "v"(hb));      \
      asm volatile("global_load_dwordx4 %0, %1, off offset:256 sc0 sc1" : "=v"(v1) : "v"(hb)); \
      asm volatile("global_load_dwordx4 %0, %1, off offset:512 sc0 sc1" : "=v"(v2) : "v"(hb)); \
      asm volatile("global_load_dwordx4 %0, %1, off offset:768 sc0 sc1" : "=v"(v3) : "v"(hb)); \
      asm volatile("global_load_dwordx4 %0, %1, off offset:1024 sc0 sc1" : "=v"(v4) : "v"(hb)); \
      asm volatile("global_load_dwordx4 %0, %1, off offset:1280 sc0 sc1" : "=v"(v5) : "v"(hb)); \
      asm volatile("global_load_dwordx4 %0, %1, off offset:1536 sc0 sc1" : "=v"(v6) : "v"(hb)); \
      asm volatile("global_load_dwordx4 %0, %1, off offset:1792 sc0 sc1" : "=v"(v7) : "v"(hb))
    ISSUE_POLLS();
    __builtin_amdgcn_sched_barrier(0);

    f32x4 a0 = {0.f, 0.f, 0.f, 0.f}, a1 = {0.f, 0.f, 0.f, 0.f};
    const char* bbase = buf + fr * ACT_STRIDE;
    const int bmask = (fr & 7) << 4;
    {   // x chunks kk = 0..3 overlap the poll latency
      bf16x8 p0 = *(const bf16x8*)(bbase + ((0 * 64 + kg * 16) ^ bmask));
      a0 = __builtin_amdgcn_mfma_f32_16x16x32_bf16(wfrag[0], p0, a0, 0, 0, 0);
      bf16x8 p1 = *(const bf16x8*)(bbase + ((1 * 64 + kg * 16) ^ bmask));
      a1 = __builtin_amdgcn_mfma_f32_16x16x32_bf16(wfrag[1], p1, a1, 0, 0, 0);
      bf16x8 p2 = *(const bf16x8*)(bbase + ((2 * 64 + kg * 16) ^ bmask));
      a0 = __builtin_amdgcn_mfma_f32_16x16x32_bf16(wfrag[2], p2, a0, 0, 0, 0);
      bf16x8 p3 = *(const bf16x8*)(bbase + ((3 * 64 + kg * 16) ^ bmask));
      a1 = __builtin_amdgcn_mfma_f32_16x16x32_bf16(wfrag[3], p3, a1, 0, 0, 0);
    }
    __builtin_amdgcn_sched_barrier(0);

    // ---- spin: all 32 tags == t  <=>  min(words) >= t<<16 (monotone slots) ----
    {
      const u32 tgt = (u32)t << 16;
      for (;;) {
        asm volatile("s_waitcnt vmcnt(0)" ::: "memory");
        __builtin_amdgcn_sched_barrier(0);   // rule #18: no hoist of checks
        u32 m0 = v0[0]; m0 = m0 < v0[1] ? m0 : v0[1];
        u32 m1 = v0[2]; m1 = m1 < v0[3] ? m1 : v0[3];
        #define MIN4(V) { m0 = m0 < V[0] ? m0 : V[0]; m0 = m0 < V[1] ? m0 : V[1]; \
                          m1 = m1 < V[2] ? m1 : V[2]; m1 = m1 < V[3] ? m1 : V[3]; }
        MIN4(v1) MIN4(v2) MIN4(v3) MIN4(v4) MIN4(v5) MIN4(v6) MIN4(v7)
        #undef MIN4
        u32 m = m0 < m1 ? m0 : m1;
        if (m >= tgt) break;
        ISSUE_POLLS();
      }
    }
    #undef ISSUE_POLLS

    // ---- unpack payloads -> act LDS h-region (contiguous 8B per thread) ----
    {
      char* dst = buf + prow * ACT_STRIDE;
      const int swz = (prow & 7) << 4;
      #define UNPACK(i, V)                                                  \
        {                                                                   \
          u32 w0 = (V[0] & 0xffffu) | (V[1] << 16);                         \
          u32 w1 = (V[2] & 0xffffu) | (V[3] << 16);                         \
          u32x2 wp = { w0, w1 };                                            \
          *(u32x2*)(dst + ((256 + 128 * (i) + 8 * pw) ^ swz)) = wp;         \
        }
      UNPACK(0, v0) UNPACK(1, v1) UNPACK(2, v2) UNPACK(3, v3)
      UNPACK(4, v4) UNPACK(5, v5) UNPACK(6, v6) UNPACK(7, v7)
      #undef UNPACK
    }
    __syncthreads();   // sync2: h region ready

    // ---- h chunks kk = 4..19 ----
    #pragma unroll
    for (int kk = 4; kk < 20; kk += 2) {
      bf16x8 b0 = *(const bf16x8*)(bbase + ((kk * 64 + kg * 16) ^ bmask));
      a0 = __builtin_amdgcn_mfma_f32_16x16x32_bf16(wfrag[kk], b0, a0, 0, 0, 0);
      bf16x8 b1 = *(const bf16x8*)(bbase + (((kk + 1) * 64 + kg * 16) ^ bmask));
      a1 = __builtin_amdgcn_mfma_f32_16x16x32_bf16(wfrag[kk + 1], b1, a1, 0, 0, 0);
    }
    f32x4 dsum = a0 + a1;

    // ---- 4x4 transpose across kg groups -> lane holds 4 gate types ----
    float d0 = dsum[0], d1 = dsum[1], d2 = dsum[2], d3 = dsum[3];
    float t0 = __shfl_xor((kg & 2) ? d0 : d2, 32, 64);
    float t1 = __shfl_xor((kg & 2) ? d1 : d3, 32, 64);
    float w0 = (kg & 2) ? t0 : d0;
    float w1 = (kg & 2) ? t1 : d1;
    float w2 = (kg & 2) ? d2 : t0;
    float w3 = (kg & 2) ? d3 : t1;
    float t2 = __shfl_xor((kg & 1) ? w0 : w1, 16, 64);
    float t3 = __shfl_xor((kg & 1) ? w2 : w3, 16, 64);
    float gi = (kg & 1) ? t2 : w0;
    float gf = (kg & 1) ? w1 : t2;
    float gg = (kg & 1) ? t3 : w2;
    float go = (kg & 1) ? w3 : t3;

    // ---- gate math + state update (1 cell per lane) ----
    float iv = sigm(gi + bi_);
    float fv = sigm(gf + bf_);
    float gv = tanh_f(gg + bg_);
    float ov = sigm(go + bo_);
    c_state = fv * c_state + iv * gv;
    float hv = ov * tanh_f(c_state);

    // ---- tagged store ----
    u32 val = ((u32)(t + 1) << 16) | bf16bits(hv);
    u32* dstp = hbuf + (size_t)((t + 1) & 1) * HSLOT + (size_t)(row0 + fr) * H_ + jcol;
    asm volatile("global_store_dword %0, %1, off sc0 sc1" :: "v"(dstp), "v"(val) : "memory");

    if (t == T_ - 1) hf32[(size_t)(row0 + fr) * H_ + jcol] = hv;
  }
}

__global__ void __launch_bounds__(64) out_kernel(
    const float* __restrict__ h_f32,
    const float* __restrict__ Wout,
    const float* __restrict__ bout,
    float* __restrict__ out)
{
  int b = blockIdx.x;
  int lane = threadIdx.x;
  float a0 = 0.f, a1 = 0.f, a2 = 0.f, a3 = 0.f;
  for (int j = lane; j < H_; j += 64) {
    float hv = fmaxf(h_f32[(size_t)b * H_ + j], 0.f);
    a0 += hv * Wout[0 * H_ + j];
    a1 += hv * Wout[1 * H_ + j];
    a2 += hv * Wout[2 * H_ + j];
    a3 += hv * Wout[3 * H_ + j];
  }
  #pragma unroll
  for (int off = 32; off; off >>= 1) {
    a0 += __shfl_down(a0, off);
    a1 += __shfl_down(a1, off);
    a2 += __shfl_down(a2, off);
    a3 += __shfl_down(a3, off);
  }
  if (lane == 0) {
    out[b * 4 + 0] = a0 + bout[0];
    out[b * 4 + 1] = a1 + bout[1];
    out[b * 4 + 2] = a2 + bout[2];
    out[b * 4 + 3] = a3 + bout[3];
  }
}

extern "C" void kernel_launch(void* const* d_in, const int* in_sizes, int n_in,
                              void* d_out, int out_size, void* d_ws, size_t ws_size,
                              hipStream_t stream) {
  const float* x    = (const float*)d_in[0];
  const float* Wih  = (const float*)d_in[1];
  const float* Whh  = (const float*)d_in[2];
  const float* bih  = (const float*)d_in[3];
  const float* bhh  = (const float*)d_in[4];
  // d_in[5..8] = layer-1 weights: dead code in the reference, unused.
  const float* Wout = (const float*)d_in[9];
  const float* bout = (const float*)d_in[10];

  char* ws = (char*)d_ws;
  u32*   hbuf = (u32*)ws;                    // 262144 B
  float* hf32 = (float*)(ws + 262144);       // 131072 B
  const size_t XBF_OFF = 393216;
  const size_t XBF_SZ = (size_t)T_ * 4 * 16 * 128 * 2;   // 33554432 B
  bf16* xbf = (ws_size >= XBF_OFF + XBF_SZ) ? (bf16*)(ws + XBF_OFF) : nullptr;

  hipLaunchKernelGGL(prep_kernel, dim3(256), dim3(NTHR), 0, stream, hbuf);
  if (xbf)
    hipLaunchKernelGGL(xconv_kernel, dim3(64, 8), dim3(NTHR), 0, stream, x, xbf);

  void* args[] = { (void*)&x, (void*)&Wih, (void*)&Whh, (void*)&bih, (void*)&bhh,
                   (void*)&hbuf, (void*)&hf32, (void*)&xbf };
  hipLaunchCooperativeKernel((void*)lstm_kernel, dim3(NBLK), dim3(NTHR),
                             args, 0, stream);

  hipLaunchKernelGGL(out_kernel, dim3(B_), dim3(64), 0, stream,
                     hf32, Wout, bout, (float*)d_out);
}